// Round 8
// baseline (3806.090 us; speedup 1.0000x reference)
//
#include <hip/hip_runtime.h>
#include <math.h>

// ODE-RNN forward: B=1024, T=100, D=32, H=256, MID=50 (padded 64), RK4x4.
// Round 8: R7 structure (wave-specialized A/B, RK4 state in regs, 2
// barriers/eval) with CORRECTED cross-lane reductions: mirror/quad_perm
// DPP butterflies (exact, group-contained, total lands in every lane)
// replacing the broken row_shr trees (R7: wrong lane + cross-group leak).

#define NT 512

// ---- ws layout (float4 units) ----
#define WF_WCAT 0        // [36][512] f4 : RNN concat weights, per-thread packed
#define WF_L1   18432    // [64][128] f4 : mu-l1 weights
#define WF_SG   26624    // [128][128] f4 : sigma-l1 weights

// ---- LDS layout ----
#define F4_YC   0        // [2][64] f4 : current y (ODE state broadcast)
#define F4_MID  128      // [2][16] f4 : mid activations
#define F4_HL   160      // [2][2][64] f4 : h double buffer [parity][row]
#define F4_X    416      // [2][8] f4 : x tile
#define F4_L1O  432      // [2][32] f4
#define F4_SG   496      // [2][64] f4
#define SM_L1B  2496     // float offsets
#define SM_SB1  2624
#define SM_MUW  2880
#define SM_SW2  3008
#define SM_SCL  3264
#define SM_TOTF 3272

__device__ __forceinline__ float fma4(float acc, float4 y, float4 w) {
  acc = fmaf(y.x, w.x, acc); acc = fmaf(y.y, w.y, acc);
  acc = fmaf(y.z, w.z, acc); acc = fmaf(y.w, w.w, acc);
  return acc;
}
__device__ __forceinline__ float4 add4(float4 a, float4 b) {
  return make_float4(a.x + b.x, a.y + b.y, a.z + b.z, a.w + b.w);
}
__device__ __forceinline__ float4 axpy4(float a, float4 xv, float4 yv) {
  return make_float4(fmaf(a, xv.x, yv.x), fmaf(a, xv.y, yv.y),
                     fmaf(a, xv.z, yv.z), fmaf(a, xv.w, yv.w));
}
__device__ __forceinline__ float4 muls4(float4 v, float s) {
  return make_float4(v.x * s, v.y * s, v.z * s, v.w * s);
}
__device__ __forceinline__ float tfast(float x) {
  float ax = fabsf(x);
  float e  = __expf(-2.f * ax);
  float t  = (1.f - e) * __builtin_amdgcn_rcpf(1.f + e);
  return copysignf(t, x);
}
__device__ __forceinline__ float4 tfast4(float4 v) {
  return make_float4(tfast(v.x), tfast(v.y), tfast(v.z), tfast(v.w));
}

// DPP butterfly adds: pure VALU, exact, group-contained. After redN, EVERY
// lane of each aligned N-lane group holds the group sum.
// quad_perm xor1 = [1,0,3,2] = 0xB1 ; quad_perm xor2 = [2,3,0,1] = 0x4E ;
// row_half_mirror = 0x141 (within 8-lane halves) ; row_mirror = 0x140.
template <int CTRL>
__device__ __forceinline__ float dpp_add(float v) {
  int s = __builtin_amdgcn_update_dpp(0, __float_as_int(v), CTRL, 0xF, 0xF, true);
  return v + __int_as_float(s);
}
__device__ __forceinline__ float red2(float v)  { return dpp_add<0xB1>(v); }
__device__ __forceinline__ float red4(float v)  { return dpp_add<0x4E>(dpp_add<0xB1>(v)); }
__device__ __forceinline__ float red8(float v)  {
  return dpp_add<0xB1>(dpp_add<0x4E>(dpp_add<0x141>(v)));
}
__device__ __forceinline__ float red16(float v) {
  return dpp_add<0xB1>(dpp_add<0x4E>(dpp_add<0x141>(dpp_add<0x140>(v))));
}

__global__ void prep_w(const float* __restrict__ Wih, const float* __restrict__ Whh,
                       const float* __restrict__ l1w, const float* __restrict__ sw1,
                       float* __restrict__ ws) {
  int i = blockIdx.x * 256 + threadIdx.x;
  if (i < 73728) {                       // wcat: [j=c*9+gg][tid 512] f4
    int fi = i >> 2, comp = i & 3;
    int j = fi >> 9, tw = fi & 511;
    int c = j / 9, gg = j - c * 9;
    int cq = tw >> 3, kc = tw & 7;
    int k = 36 * kc + 4 * gg + comp, col = 4 * cq + c;
    ws[i] = (k < 32) ? Wih[col * 32 + k] : Whh[col * 256 + (k - 32)];
  } else if (i < 73728 + 32768) {        // l1: [j=c*16+jj][t7 128] f4
    int t = i - 73728;
    int fi = t >> 2, comp = t & 3;
    int j = fi >> 7, tt = fi & 127;
    int c = j >> 4, jj = j & 15;
    int cq = tt >> 2, kc = tt & 3;
    int k = 4 * (4 * jj + kc) + comp, col = 4 * cq + c;
    ws[73728 + t] = l1w[col * 256 + k];
  } else if (i < 172032) {               // sig: [j=c*32+jj][t7 128] f4
    int t = i - 106496;
    int fi = t >> 2, comp = t & 3;
    int j = fi >> 7, tt = fi & 127;
    int c = j >> 5, jj = j & 31;
    int cq = tt >> 1, kc = tt & 1;
    int k = 4 * (2 * jj + kc) + comp, col = 4 * cq + c;
    ws[106496 + t] = sw1[col * 256 + k];
  }
}

__device__ __forceinline__ void rnn_phase(int tid, int pOld, const float4* __restrict__ wc4,
                                          float4* smf4, float4 bcR) {
  const int cq = tid >> 3, kc = tid & 7;
  float a0 = 0, a1 = 0, a2 = 0, a3 = 0, a4 = 0, a5 = 0, a6 = 0, a7 = 0;
#pragma unroll 1
  for (int gg = 0; gg < 9; ++gg) {
    int g = kc * 9 + gg;
    int i0 = (g < 8) ? (F4_X + g) : (F4_HL + pOld * 128 + (g - 8));
    int i1 = (g < 8) ? (F4_X + 8 + g) : (F4_HL + pOld * 128 + 64 + (g - 8));
    float4 y0 = smf4[i0];
    float4 y1 = smf4[i1];
    float4 w0 = wc4[(0 * 9 + gg) * 512 + tid];
    float4 w1 = wc4[(1 * 9 + gg) * 512 + tid];
    float4 w2 = wc4[(2 * 9 + gg) * 512 + tid];
    float4 w3 = wc4[(3 * 9 + gg) * 512 + tid];
    a0 = fma4(a0, y0, w0); a1 = fma4(a1, y0, w1);
    a2 = fma4(a2, y0, w2); a3 = fma4(a3, y0, w3);
    a4 = fma4(a4, y1, w0); a5 = fma4(a5, y1, w1);
    a6 = fma4(a6, y1, w2); a7 = fma4(a7, y1, w3);
  }
  a0 = red8(a0); a1 = red8(a1); a2 = red8(a2); a3 = red8(a3);
  a4 = red8(a4); a5 = red8(a5); a6 = red8(a6); a7 = red8(a7);
  if (kc == 0) {
    float4 h0 = smf4[F4_HL + pOld * 128 + cq];
    float4 h1 = smf4[F4_HL + pOld * 128 + 64 + cq];
    float4 n0 = add4(h0, tfast4(add4(make_float4(a0, a1, a2, a3), bcR)));
    float4 n1 = add4(h1, tfast4(add4(make_float4(a4, a5, a6, a7), bcR)));
    int pN = pOld ^ 1;
    smf4[F4_HL + pN * 128 + cq] = n0;
    smf4[F4_HL + pN * 128 + 64 + cq] = n1;
    smf4[F4_YC + cq] = n0;
    smf4[F4_YC + 64 + cq] = n1;
  }
}

__global__ __attribute__((amdgpu_flat_work_group_size(NT, NT)))
__attribute__((amdgpu_waves_per_eu(4)))
void odernn_main(const float* __restrict__ dt,
                 const float* __restrict__ x,
                 const float* __restrict__ bih,
                 const float* __restrict__ bhh,
                 const float* __restrict__ ow1,
                 const float* __restrict__ ob1g,
                 const float* __restrict__ ow2,
                 const float* __restrict__ ob2g,
                 const float* __restrict__ l1bg,
                 const float* __restrict__ muwg,
                 const float* __restrict__ mubg,
                 const float* __restrict__ sb1g,
                 const float* __restrict__ sw2g,
                 const float* __restrict__ sb2g,
                 const float* __restrict__ ws,
                 float* __restrict__ out) {
  __shared__ __align__(16) float sm[SM_TOTF];
  float4* smf4 = (float4*)sm;
  const int tid = threadIdx.x;
  const int b0 = blockIdx.x * 2;

  const float4* wc4  = (const float4*)ws + WF_WCAT;
  const float4* l1s4 = (const float4*)ws + WF_L1;
  const float4* sgs4 = (const float4*)ws + WF_SG;

  const int cqR = tid >> 3;
  float4 bcR = make_float4(bih[4 * cqR + 0] + bhh[4 * cqR + 0],
                           bih[4 * cqR + 1] + bhh[4 * cqR + 1],
                           bih[4 * cqR + 2] + bhh[4 * cqR + 2],
                           bih[4 * cqR + 3] + bhh[4 * cqR + 3]);

  // prologue staging
  if (tid < 128) { sm[SM_L1B + tid] = l1bg[tid]; sm[SM_MUW + tid] = muwg[tid]; }
  if (tid < 256) { sm[SM_SB1 + tid] = sb1g[tid]; sm[SM_SW2 + tid] = sw2g[tid]; }
  if (tid < 128) smf4[F4_HL + tid] = make_float4(0.f, 0.f, 0.f, 0.f);
  if (tid < 16) {
    int r = tid >> 3, g = tid & 7;
    smf4[F4_X + tid] = ((const float4*)x)[((size_t)(b0 + r) * 100) * 8 + g];
  } else if (tid < 18) {
    const float* dp = dt + ((size_t)(b0 + tid - 16) * 100) * 2;
    sm[SM_SCL + tid - 16] = (dp[1] - dp[0]) * (1.f / 24.f);
  }
  __syncthreads();

  if (tid < 256) {
    // ================= A side: ode layer-1 + mu head =================
    const int q1 = tid >> 4, kc1 = tid & 15;
    float4 w1r[16];
#pragma unroll
    for (int n = 0; n < 4; ++n) {
      int row = 4 * q1 + n;
#pragma unroll
      for (int j = 0; j < 4; ++j)
        w1r[n * 4 + j] = (row < 50)
            ? *(const float4*)&ow1[row * 256 + 64 * j + 4 * kc1]
            : make_float4(0.f, 0.f, 0.f, 0.f);
    }
    float4 ob1r = make_float4(4 * q1 + 0 < 50 ? ob1g[4 * q1 + 0] : 0.f,
                              4 * q1 + 1 < 50 ? ob1g[4 * q1 + 1] : 0.f,
                              4 * q1 + 2 < 50 ? ob1g[4 * q1 + 2] : 0.f,
                              4 * q1 + 3 < 50 ? ob1g[4 * q1 + 3] : 0.f);
    const int rH = tid >> 7, cqH = (tid >> 2) & 31, kcH = tid & 3;
    const int t7 = tid & 127;
    const float mubv = mubg[0];

    for (int t = 0; t < 100; ++t) {
      const int pOld = t & 1, pNew = pOld ^ 1;
      rnn_phase(tid, pOld, wc4, smf4, bcR);
      __syncthreads();                                       // #1: h ready
#pragma unroll 1
      for (int e = 0; e < 16; ++e) {
        float a0 = 0, a1 = 0, a2 = 0, a3 = 0, a4 = 0, a5 = 0, a6 = 0, a7 = 0;
#pragma unroll
        for (int j = 0; j < 4; ++j) {
          float4 y0 = smf4[F4_YC + 16 * j + kc1];
          float4 y1 = smf4[F4_YC + 64 + 16 * j + kc1];
          a0 = fma4(a0, y0, w1r[0 * 4 + j]); a1 = fma4(a1, y0, w1r[1 * 4 + j]);
          a2 = fma4(a2, y0, w1r[2 * 4 + j]); a3 = fma4(a3, y0, w1r[3 * 4 + j]);
          a4 = fma4(a4, y1, w1r[0 * 4 + j]); a5 = fma4(a5, y1, w1r[1 * 4 + j]);
          a6 = fma4(a6, y1, w1r[2 * 4 + j]); a7 = fma4(a7, y1, w1r[3 * 4 + j]);
        }
        a0 = red16(a0); a1 = red16(a1); a2 = red16(a2); a3 = red16(a3);
        a4 = red16(a4); a5 = red16(a5); a6 = red16(a6); a7 = red16(a7);
        if (kc1 == 0) {
          smf4[F4_MID + q1]      = tfast4(add4(make_float4(a0, a1, a2, a3), ob1r));
          smf4[F4_MID + 16 + q1] = tfast4(add4(make_float4(a4, a5, a6, a7), ob1r));
        }
        __syncthreads();                                     // mid ready
        __syncthreads();                                     // yc ready (B wrote)
      }
      // heads: mu l1 partials
      float c0 = 0, c1 = 0, c2 = 0, c3 = 0;
#pragma unroll 2
      for (int jj = 0; jj < 16; ++jj) {
        float4 h = smf4[F4_HL + pNew * 128 + rH * 64 + 4 * jj + kcH];
        c0 = fma4(c0, h, l1s4[(0 * 16 + jj) * 128 + t7]);
        c1 = fma4(c1, h, l1s4[(1 * 16 + jj) * 128 + t7]);
        c2 = fma4(c2, h, l1s4[(2 * 16 + jj) * 128 + t7]);
        c3 = fma4(c3, h, l1s4[(3 * 16 + jj) * 128 + t7]);
      }
      c0 = red4(c0); c1 = red4(c1); c2 = red4(c2); c3 = red4(c3);
      if (kcH == 0) {
        float4 b = ((const float4*)(sm + SM_L1B))[cqH];
        float4 v = add4(make_float4(c0, c1, c2, c3), b);
        smf4[F4_L1O + rH * 32 + cqH] =
            make_float4(fmaxf(v.x, 0.f), fmaxf(v.y, 0.f), fmaxf(v.z, 0.f), fmaxf(v.w, 0.f));
      }
      if (t < 99) {                      // stage next x / scl
        if (tid < 16) {
          int r = tid >> 3, g = tid & 7;
          smf4[F4_X + tid] = ((const float4*)x)[((size_t)(b0 + r) * 100 + t + 1) * 8 + g];
        } else if (tid < 18) {
          const float* dp = dt + ((size_t)(b0 + tid - 16) * 100 + t + 1) * 2;
          sm[SM_SCL + tid - 16] = (dp[1] - dp[0]) * (1.f / 24.f);
        }
      }
      __syncthreads();                                       // #34: l1o/sg ready
      int wv = tid >> 6, ln = tid & 63;
      if (wv < 2) {
        float pm = 0.f;
        if (ln < 32) {
          float4 l = smf4[F4_L1O + wv * 32 + ln];
          float4 w = ((const float4*)(sm + SM_MUW))[ln];
          pm = l.x * w.x + l.y * w.y + l.z * w.z + l.w * w.w;
        }
#pragma unroll
        for (int off = 32; off > 0; off >>= 1) pm += __shfl_down(pm, off);
        if (ln == 0) out[(size_t)(b0 + wv) * 100 + t] = pm + mubv;
      }
    }
  } else {
    // ================= B side: ode layer-2 + RK4 + sigma head =================
    const int tid2 = tid - 256;
    const int cqB = tid2 >> 2, kc2 = tid2 & 3;
    float4 w2r[16];
#pragma unroll
    for (int c = 0; c < 4; ++c) {
      int col = 4 * cqB + c;
#pragma unroll
      for (int j = 0; j < 4; ++j) {
        float w0v[4];
#pragma unroll
        for (int cc = 0; cc < 4; ++cc) {
          int k = 16 * j + 4 * kc2 + cc;
          w0v[cc] = (k < 50) ? ow2[col * 50 + k] : 0.f;
        }
        w2r[c * 4 + j] = make_float4(w0v[0], w0v[1], w0v[2], w0v[3]);
      }
    }
    float4 ob2r = make_float4(ob2g[4 * cqB + 0], ob2g[4 * cqB + 1],
                              ob2g[4 * cqB + 2], ob2g[4 * cqB + 3]);
    const int rH = tid2 >> 7, cqH = (tid2 >> 1) & 63, kcH = tid2 & 1;
    const int t7 = tid2 & 127;
    const float sb2v = sb2g[0];

    for (int t = 0; t < 100; ++t) {
      const int pOld = t & 1, pNew = pOld ^ 1;
      rnn_phase(tid, pOld, wc4, smf4, bcR);
      __syncthreads();                                       // #1: h ready
      float s0 = sm[SM_SCL + 0], s1 = sm[SM_SCL + 1];
      float4 h0 = smf4[F4_YC + cqB];                         // post-RNN h
      float4 h1 = smf4[F4_YC + 64 + cqB];
      float4 ac0 = make_float4(0, 0, 0, 0), ac1 = ac0;
#pragma unroll 1
      for (int os = 0; os < 4; ++os) {
#pragma unroll
        for (int s = 0; s < 4; ++s) {
          __syncthreads();                                   // mid ready
          float b0 = 0, b1 = 0, b2 = 0, b3 = 0, b4 = 0, b5 = 0, b6 = 0, b7 = 0;
#pragma unroll
          for (int j = 0; j < 4; ++j) {
            float4 m0 = smf4[F4_MID + 4 * j + kc2];
            float4 m1 = smf4[F4_MID + 16 + 4 * j + kc2];
            b0 = fma4(b0, m0, w2r[0 * 4 + j]); b1 = fma4(b1, m0, w2r[1 * 4 + j]);
            b2 = fma4(b2, m0, w2r[2 * 4 + j]); b3 = fma4(b3, m0, w2r[3 * 4 + j]);
            b4 = fma4(b4, m1, w2r[0 * 4 + j]); b5 = fma4(b5, m1, w2r[1 * 4 + j]);
            b6 = fma4(b6, m1, w2r[2 * 4 + j]); b7 = fma4(b7, m1, w2r[3 * 4 + j]);
          }
          b0 = red4(b0); b1 = red4(b1); b2 = red4(b2); b3 = red4(b3);
          b4 = red4(b4); b5 = red4(b5); b6 = red4(b6); b7 = red4(b7);
          float4 k0 = muls4(add4(make_float4(b0, b1, b2, b3), ob2r), s0);
          float4 k1 = muls4(add4(make_float4(b4, b5, b6, b7), ob2r), s1);
          float4 y0w, y1w;
          if (s == 0) {
            ac0 = k0; ac1 = k1;
            y0w = axpy4(0.125f, k0, h0); y1w = axpy4(0.125f, k1, h1);
          } else if (s == 1) {
            ac0 = axpy4(2.f, k0, ac0); ac1 = axpy4(2.f, k1, ac1);
            y0w = axpy4(0.125f, k0, h0); y1w = axpy4(0.125f, k1, h1);
          } else if (s == 2) {
            ac0 = axpy4(2.f, k0, ac0); ac1 = axpy4(2.f, k1, ac1);
            y0w = axpy4(0.25f, k0, h0); y1w = axpy4(0.25f, k1, h1);
          } else {
            h0 = axpy4(0.25f / 6.f, add4(ac0, k0), h0);
            h1 = axpy4(0.25f / 6.f, add4(ac1, k1), h1);
            y0w = h0; y1w = h1;
          }
          if (kc2 == 0) {
            smf4[F4_YC + cqB] = y0w;
            smf4[F4_YC + 64 + cqB] = y1w;
            if (os == 3 && s == 3) {
              smf4[F4_HL + pNew * 128 + cqB] = h0;
              smf4[F4_HL + pNew * 128 + 64 + cqB] = h1;
            }
          }
          __syncthreads();                                   // yc ready
        }
      }
      // heads: sigma l1 partials
      float d0 = 0, d1 = 0, d2 = 0, d3 = 0;
#pragma unroll 2
      for (int jj = 0; jj < 32; ++jj) {
        float4 h = smf4[F4_HL + pNew * 128 + rH * 64 + 2 * jj + kcH];
        d0 = fma4(d0, h, sgs4[(0 * 32 + jj) * 128 + t7]);
        d1 = fma4(d1, h, sgs4[(1 * 32 + jj) * 128 + t7]);
        d2 = fma4(d2, h, sgs4[(2 * 32 + jj) * 128 + t7]);
        d3 = fma4(d3, h, sgs4[(3 * 32 + jj) * 128 + t7]);
      }
      d0 = red2(d0); d1 = red2(d1); d2 = red2(d2); d3 = red2(d3);
      if (kcH == 0) {
        float4 sb = ((const float4*)(sm + SM_SB1))[cqH];
        smf4[F4_SG + rH * 64 + cqH] = tfast4(add4(make_float4(d0, d1, d2, d3), sb));
      }
      __syncthreads();                                       // #34: l1o/sg ready
      int wv = tid >> 6, ln = tid & 63;
      if (wv < 6) {                                          // waves 4,5
        int r = wv - 4;
        float4 sv = smf4[F4_SG + r * 64 + ln];
        float4 w = ((const float4*)(sm + SM_SW2))[ln];
        float ps = sv.x * w.x + sv.y * w.y + sv.z * w.z + sv.w * w.w;
#pragma unroll
        for (int off = 32; off > 0; off >>= 1) ps += __shfl_down(ps, off);
        if (ln == 0) {
          float z = ps + sb2v;
          float sp = fmaxf(z, 0.f) + log1pf(expf(-fabsf(z)));
          out[(size_t)102400 + (size_t)(b0 + r) * 100 + t] = sp;
        }
      }
    }
  }
}

extern "C" void kernel_launch(void* const* d_in, const int* in_sizes, int n_in,
                              void* d_out, int out_size, void* d_ws, size_t ws_size,
                              hipStream_t stream) {
  const float* dt  = (const float*)d_in[0];
  const float* x   = (const float*)d_in[1];
  const float* Wih = (const float*)d_in[2];
  const float* bih = (const float*)d_in[3];
  const float* Whh = (const float*)d_in[4];
  const float* bhh = (const float*)d_in[5];
  const float* ow1 = (const float*)d_in[6];
  const float* ob1 = (const float*)d_in[7];
  const float* ow2 = (const float*)d_in[8];
  const float* ob2 = (const float*)d_in[9];
  const float* l1w = (const float*)d_in[10];
  const float* l1b = (const float*)d_in[11];
  const float* muw = (const float*)d_in[12];
  const float* mub = (const float*)d_in[13];
  const float* sw1 = (const float*)d_in[14];
  const float* sb1 = (const float*)d_in[15];
  const float* sw2 = (const float*)d_in[16];
  const float* sb2 = (const float*)d_in[17];
  float* ws  = (float*)d_ws;
  float* out = (float*)d_out;

  prep_w<<<672, 256, 0, stream>>>(Wih, Whh, l1w, sw1, ws);
  odernn_main<<<512, NT, 0, stream>>>(dt, x, bih, bhh, ow1, ob1, ow2, ob2,
                                      l1b, muw, mub, sb1, sw2, sb2, ws, out);
}